// Round 2
// baseline (955.621 us; speedup 1.0000x reference)
//
#include <hip/hip_runtime.h>
#include <hip/hip_bf16.h>

#define BB 8
#define RR 100
#define IW 64
#define OW 16
#define DD 128
#define BD 32

// ---------------- Stage A: xn, q-MLP (per-region), kv-MLP, K, V, Vn ----------
__global__ __launch_bounds__(256) void stage_a(
    const float* __restrict__ x, const float* __restrict__ mean, const float* __restrict__ stddev,
    const float* __restrict__ kv_in_W, const float* __restrict__ kv_in_b,
    const float* __restrict__ kv_blk_W, const float* __restrict__ kv_blk_b,
    const float* __restrict__ q_in_W, const float* __restrict__ q_in_b,
    const float* __restrict__ q_blk_W, const float* __restrict__ q_blk_b,
    const float* __restrict__ key_W, const float* __restrict__ key_b,
    const float* __restrict__ value_W, const float* __restrict__ value_b,
    float* __restrict__ q_t,   // [R][D][B]
    float* __restrict__ K_t,   // [R][D][B]
    float* __restrict__ Vn)    // [B][R][BD]
{
    const int r = blockIdx.x, tid = threadIdx.x;
    __shared__ float xn_s[BB][IW];   // 2 KB
    __shared__ float h_s[BB][DD];    // 4 KB
    __shared__ float g_s[BB][DD];    // 4 KB
    __shared__ float V_s[BB][BD];    // 1 KB
    __shared__ float nrm_s[BB];

    const float mu = mean[r];
    const float sd = stddev[r] + 1e-8f;

    for (int idx = tid; idx < BB * IW; idx += 256) {
        int b = idx >> 6, i = idx & 63;
        xn_s[b][i] = (x[(b * RR + r) * IW + i] - mu) / sd;
    }
    __syncthreads();

    const int j = tid & 127, b0 = tid >> 7;   // b = b0 + 2k, k=0..3

    // q layer 1: relu(xn @ q_in_W[r] + q_in_b[r]) -> h_s
    {
        float acc[4];
        const float bias = q_in_b[r * DD + j];
        #pragma unroll
        for (int k = 0; k < 4; k++) acc[k] = bias;
        const float* W = q_in_W + (size_t)r * IW * DD;
        for (int i = 0; i < IW; i++) {
            float w = W[i * DD + j];
            #pragma unroll
            for (int k = 0; k < 4; k++) acc[k] = fmaf(xn_s[b0 + 2 * k][i], w, acc[k]);
        }
        #pragma unroll
        for (int k = 0; k < 4; k++) h_s[b0 + 2 * k][j] = fmaxf(acc[k], 0.f);
    }
    __syncthreads();

    // q layer 2 -> q_t[(r*D+e)*B+b]
    {
        float acc[4];
        const float bias = q_blk_b[r * DD + j];
        #pragma unroll
        for (int k = 0; k < 4; k++) acc[k] = bias;
        const float* W = q_blk_W + (size_t)r * DD * DD;
        for (int i = 0; i < DD; i++) {
            float w = W[i * DD + j];
            #pragma unroll
            for (int k = 0; k < 4; k++) acc[k] = fmaf(h_s[b0 + 2 * k][i], w, acc[k]);
        }
        #pragma unroll
        for (int k = 0; k < 4; k++) q_t[((size_t)r * DD + j) * BB + b0 + 2 * k] = acc[k];
    }
    __syncthreads();   // before reusing h_s

    // kv layer 1: relu(xn @ kv_in_W + kv_in_b) -> h_s
    {
        float acc[4];
        const float bias = kv_in_b[j];
        #pragma unroll
        for (int k = 0; k < 4; k++) acc[k] = bias;
        for (int i = 0; i < IW; i++) {
            float w = kv_in_W[i * DD + j];
            #pragma unroll
            for (int k = 0; k < 4; k++) acc[k] = fmaf(xn_s[b0 + 2 * k][i], w, acc[k]);
        }
        #pragma unroll
        for (int k = 0; k < 4; k++) h_s[b0 + 2 * k][j] = fmaxf(acc[k], 0.f);
    }
    __syncthreads();

    // kv layer 2 (no relu) -> g_s
    {
        float acc[4];
        const float bias = kv_blk_b[j];
        #pragma unroll
        for (int k = 0; k < 4; k++) acc[k] = bias;
        for (int i = 0; i < DD; i++) {
            float w = kv_blk_W[i * DD + j];
            #pragma unroll
            for (int k = 0; k < 4; k++) acc[k] = fmaf(h_s[b0 + 2 * k][i], w, acc[k]);
        }
        #pragma unroll
        for (int k = 0; k < 4; k++) g_s[b0 + 2 * k][j] = acc[k];
    }
    __syncthreads();

    // K = kv @ key_W + key_b -> K_t[(r*D+e)*B+b]
    {
        float acc[4];
        const float bias = key_b[j];
        #pragma unroll
        for (int k = 0; k < 4; k++) acc[k] = bias;
        for (int i = 0; i < DD; i++) {
            float w = key_W[i * DD + j];
            #pragma unroll
            for (int k = 0; k < 4; k++) acc[k] = fmaf(g_s[b0 + 2 * k][i], w, acc[k]);
        }
        #pragma unroll
        for (int k = 0; k < 4; k++) K_t[((size_t)r * DD + j) * BB + b0 + 2 * k] = acc[k];
    }

    // V = kv @ value_W + value_b  (8*32 = 256 outputs, one per thread)
    {
        int b = tid >> 5, c = tid & 31;
        float acc = value_b[c];
        for (int i = 0; i < DD; i++) acc = fmaf(g_s[b][i], value_W[i * BD + c], acc);
        V_s[b][c] = acc;
    }
    __syncthreads();
    if (tid < BB) {
        float s = 0.f;
        for (int c = 0; c < BD; c++) s = fmaf(V_s[tid][c], V_s[tid][c], s);
        nrm_s[tid] = 1.f / fmaxf(sqrtf(s), 1e-12f);
    }
    __syncthreads();
    {
        int b = tid >> 5, c = tid & 31;
        Vn[((size_t)b * RR + r) * BD + c] = V_s[b][c] * nrm_s[b];
    }
}

// ---------------- Stage B: attention logits (the 655 MB streaming kernel) ----
// grid (25, 100); block 256 = 4 waves; wave w handles tile (s = blockIdx.y,
// t = blockIdx.x*4 + w). Lane l covers columns d = 4*(l&31)..+3 of the rows
// i + (l>>5) as i steps by 2, so one wave-wide float4 load = 2 full rows (1KB).
__global__ __launch_bounds__(256) void stage_b(
    const float* __restrict__ qw,   // [R][R][D][D]
    const float* __restrict__ qb,   // [R][R][D]
    const float* __restrict__ q_t,  // [R][D][B]
    const float* __restrict__ K_t,  // [R][D][B]
    float* __restrict__ attn)       // [B][R][R] relu'd logits
{
    const int s = blockIdx.y;
    const int t = blockIdx.x * 4 + (threadIdx.x >> 6);
    const int lane = threadIdx.x & 63;
    const int half = lane >> 5;
    const int l31 = lane & 31;

    __shared__ float q_ls[DD * BB];   // [i][b], 4 KB
    {
        const float4* src = reinterpret_cast<const float4*>(q_t + (size_t)s * DD * BB);
        reinterpret_cast<float4*>(q_ls)[threadIdx.x] = src[threadIdx.x];
    }
    __syncthreads();

    const float* wp = qw + ((size_t)(s * RR + t)) * DD * DD + half * DD + l31 * 4;

    float tc[4][BB];
    #pragma unroll
    for (int jj = 0; jj < 4; jj++)
        #pragma unroll
        for (int b = 0; b < BB; b++) tc[jj][b] = 0.f;

    #pragma unroll 4
    for (int i = 0; i < DD; i += 2) {
        float4 wv = *reinterpret_cast<const float4*>(wp + (size_t)i * DD);
        const float* qp = q_ls + (i + half) * BB;
        float4 qa = *reinterpret_cast<const float4*>(qp);
        float4 qc = *reinterpret_cast<const float4*>(qp + 4);
        float qv[BB] = {qa.x, qa.y, qa.z, qa.w, qc.x, qc.y, qc.z, qc.w};
        float wj[4] = {wv.x, wv.y, wv.z, wv.w};
        #pragma unroll
        for (int jj = 0; jj < 4; jj++)
            #pragma unroll
            for (int b = 0; b < BB; b++)
                tc[jj][b] = fmaf(wj[jj], qv[b], tc[jj][b]);
    }

    // bias (count once: lower half only)
    float qbj[4] = {0.f, 0.f, 0.f, 0.f};
    if (half == 0) {
        float4 qb4 = *reinterpret_cast<const float4*>(qb + (size_t)(s * RR + t) * DD + l31 * 4);
        qbj[0] = qb4.x; qbj[1] = qb4.y; qbj[2] = qb4.z; qbj[3] = qb4.w;
    }

    float p[BB];
    #pragma unroll
    for (int b = 0; b < BB; b++) p[b] = 0.f;
    #pragma unroll
    for (int jj = 0; jj < 4; jj++) {
        int d = l31 * 4 + jj;
        const float* kp = K_t + ((size_t)t * DD + d) * BB;
        float4 k0 = *reinterpret_cast<const float4*>(kp);
        float4 k1 = *reinterpret_cast<const float4*>(kp + 4);
        float kk[BB] = {k0.x, k0.y, k0.z, k0.w, k1.x, k1.y, k1.z, k1.w};
        #pragma unroll
        for (int b = 0; b < BB; b++)
            p[b] = fmaf(tc[jj][b] + qbj[jj], kk[b], p[b]);
    }

    // butterfly reduce across 64 lanes
    #pragma unroll
    for (int b = 0; b < BB; b++) {
        float v = p[b];
        #pragma unroll
        for (int off = 32; off >= 1; off >>= 1) v += __shfl_xor(v, off, 64);
        p[b] = v;
    }
    if (lane == 0) {
        #pragma unroll
        for (int b = 0; b < BB; b++)
            attn[((size_t)b * RR + s) * RR + t] = fmaxf(p[b], 0.f);
    }
}

// ---------------- Stage C: normalize, attn@Vn, reproj, post, out, rescale ----
__global__ __launch_bounds__(256) void stage_c(
    const float* __restrict__ attn, const float* __restrict__ Vn,
    const float* __restrict__ reproj_W, const float* __restrict__ reproj_b,
    const float* __restrict__ post_blk_W, const float* __restrict__ post_blk_b,
    const float* __restrict__ out_W, const float* __restrict__ out_b,
    const float* __restrict__ mean, const float* __restrict__ stddev,
    float* __restrict__ out)
{
    const int s = blockIdx.x, tid = threadIdx.x;
    __shared__ float a_s[BB][RR];    // 3.2 KB
    __shared__ float dnm[BB];
    __shared__ float ao_s[BB][BD];   // 1 KB
    __shared__ float h1_s[BB][DD];   // 4 KB
    __shared__ float h2_s[BB][DD];   // 4 KB

    for (int idx = tid; idx < BB * RR; idx += 256) {
        int b = idx / RR, t = idx - b * RR;
        a_s[b][t] = attn[((size_t)b * RR + s) * RR + t];
    }
    __syncthreads();
    if (tid < BB) {
        float sum = 0.f;
        for (int t = 0; t < RR; t++) sum += a_s[tid][t];
        dnm[tid] = 1.f / (1e-8f + sum);
    }
    __syncthreads();

    // att_out = (attn/denom) @ Vn  -> ao_s
    {
        int b = tid >> 5, c = tid & 31;
        float acc = 0.f;
        for (int t = 0; t < RR; t++)
            acc = fmaf(a_s[b][t], Vn[((size_t)b * RR + t) * BD + c], acc);
        ao_s[b][c] = acc * dnm[b];
    }
    __syncthreads();

    const int j = tid & 127, b0 = tid >> 7;

    // reproj + relu -> h1_s
    {
        float acc[4];
        const float bias = reproj_b[j];
        #pragma unroll
        for (int k = 0; k < 4; k++) acc[k] = bias;
        for (int c = 0; c < BD; c++) {
            float w = reproj_W[c * DD + j];
            #pragma unroll
            for (int k = 0; k < 4; k++) acc[k] = fmaf(ao_s[b0 + 2 * k][c], w, acc[k]);
        }
        #pragma unroll
        for (int k = 0; k < 4; k++) h1_s[b0 + 2 * k][j] = fmaxf(acc[k], 0.f);
    }
    __syncthreads();

    // post block -> h2_s (no relu)
    {
        float acc[4];
        const float bias = post_blk_b[s * DD + j];
        #pragma unroll
        for (int k = 0; k < 4; k++) acc[k] = bias;
        const float* W = post_blk_W + (size_t)s * DD * DD;
        for (int i = 0; i < DD; i++) {
            float w = W[i * DD + j];
            #pragma unroll
            for (int k = 0; k < 4; k++) acc[k] = fmaf(h1_s[b0 + 2 * k][i], w, acc[k]);
        }
        #pragma unroll
        for (int k = 0; k < 4; k++) h2_s[b0 + 2 * k][j] = acc[k];
    }
    __syncthreads();

    // out proj + rescale; 8*16 = 128 outputs
    if (tid < BB * OW) {
        int b = tid >> 4, o = tid & 15;
        float acc = out_b[s * OW + o];
        const float* W = out_W + (size_t)s * DD * OW;
        for (int e = 0; e < DD; e++) acc = fmaf(h2_s[b][e], W[e * OW + o], acc);
        out[((size_t)b * RR + s) * OW + o] = acc * stddev[s] + mean[s];
    }
}

extern "C" void kernel_launch(void* const* d_in, const int* in_sizes, int n_in,
                              void* d_out, int out_size, void* d_ws, size_t ws_size,
                              hipStream_t stream) {
    const float* x           = (const float*)d_in[0];
    const float* mean        = (const float*)d_in[1];
    const float* stddev      = (const float*)d_in[2];
    const float* kv_in_W     = (const float*)d_in[3];
    const float* kv_in_b     = (const float*)d_in[4];
    const float* kv_blk_W    = (const float*)d_in[5];
    const float* kv_blk_b    = (const float*)d_in[6];
    const float* q_in_W      = (const float*)d_in[7];
    const float* q_in_b      = (const float*)d_in[8];
    const float* q_blk_W     = (const float*)d_in[9];
    const float* q_blk_b     = (const float*)d_in[10];
    const float* key_W       = (const float*)d_in[11];
    const float* key_b       = (const float*)d_in[12];
    const float* value_W     = (const float*)d_in[13];
    const float* value_b     = (const float*)d_in[14];
    const float* query_weight= (const float*)d_in[15];
    const float* query_bias  = (const float*)d_in[16];
    const float* reproj_W    = (const float*)d_in[17];
    const float* reproj_b    = (const float*)d_in[18];
    const float* post_blk_W  = (const float*)d_in[19];
    const float* post_blk_b  = (const float*)d_in[20];
    const float* out_W       = (const float*)d_in[21];
    const float* out_b       = (const float*)d_in[22];

    float* ws   = (float*)d_ws;
    float* q_t  = ws;                 // R*D*B = 102400
    float* K_t  = ws + 102400;        // 102400
    float* Vn   = ws + 204800;        // B*R*BD = 25600
    float* attn = ws + 230400;        // B*R*R = 80000
    float* out  = (float*)d_out;

    hipLaunchKernelGGL(stage_a, dim3(RR), dim3(256), 0, stream,
        x, mean, stddev, kv_in_W, kv_in_b, kv_blk_W, kv_blk_b,
        q_in_W, q_in_b, q_blk_W, q_blk_b, key_W, key_b, value_W, value_b,
        q_t, K_t, Vn);

    hipLaunchKernelGGL(stage_b, dim3(25, RR), dim3(256), 0, stream,
        query_weight, query_bias, q_t, K_t, attn);

    hipLaunchKernelGGL(stage_c, dim3(RR), dim3(256), 0, stream,
        attn, Vn, reproj_W, reproj_b, post_blk_W, post_blk_b,
        out_W, out_b, mean, stddev, out);
}